// Round 2
// baseline (117.836 us; speedup 1.0000x reference)
//
#include <hip/hip_runtime.h>
#include <math.h>

// N=M=8192, d=64, P=64, N_FT=1024 -> folded k = 1..512, active band contiguous
#define N_SRC 8192
#define D_DIM 64
#define P_SL  64
#define KH    512

// ws float offsets. NO host memset: WS_NM uses int atomicMax (0xAAAAAAAA poison
// is negative int -> loses to any positive float bits); CS/out zeroed by kA.
#define WS_NM    0                       // norm_max as float bits, int atomicMax
#define WS_CS    16                      // wk*C, wk*S per (p, k-kmin): P*KH*2
#define WS_A     (WS_CS + P_SL*KH*2)     // UNSCALED projections of x: P*N
#define WS_B2    (WS_A + P_SL*N_SRC)     // UNSCALED projections of y: P*N

#define LOG_THRESH (-23.0259f)           // ln(1e-10): tail adds <1e-6 to out
#define LGAMMA32    78.0922236f
#define TWO_PI2     19.7392088f

__device__ __forceinline__ void sincos2pi(float t, float& s, float& c) {
    // v_sin_f32 / v_cos_f32 take REVOLUTIONS; fract maps into valid range.
    float f = __builtin_amdgcn_fractf(t);
    s = __builtin_amdgcn_sinf(f);
    c = __builtin_amdgcn_cosf(f);
}

// kA: row norms (int atomicMax), unscaled projections, inline zeroing of CS
// accumulators and out. Restructured: q in {0,1} (2 slice-halves, 32 p each)
// so each row is fetched 2x (8.4 MB) instead of 8x (33.6 MB). pi unrolled x4
// for four independent FMA chains. grid 128 x 256.
__global__ __launch_bounds__(256) void kA(const float* __restrict__ x,
                                          const float* __restrict__ y,
                                          const float* __restrict__ xis,
                                          float* __restrict__ ws,
                                          float* __restrict__ out) {
    int tid = threadIdx.x, b = blockIdx.x;
    int rblk = b & 63, q = b >> 6;          // q in [0,2): slice half, block-uniform
    int r = rblk * 256 + tid;               // 0..16383 over [x; y]
    int isx = (r < N_SRC);
    const float* src = isx ? (x + (size_t)r * D_DIM)
                           : (y + (size_t)(r - N_SRC) * D_DIM);
    float4 row[16];
    const float4* rp = (const float4*)src;
#pragma unroll
    for (int j = 0; j < 16; ++j) row[j] = rp[j];

    if (q == 0) {  // 64 blocks cover all 16384 rows for the norm
        float ss = 0.f;
#pragma unroll
        for (int j = 0; j < 16; ++j) {
            ss = fmaf(row[j].x, row[j].x, ss); ss = fmaf(row[j].y, row[j].y, ss);
            ss = fmaf(row[j].z, row[j].z, ss); ss = fmaf(row[j].w, row[j].w, ss);
        }
        float nm = sqrtf(ss);
        for (int o = 32; o; o >>= 1) nm = fmaxf(nm, __shfl_xor(nm, o, 64));
        if ((tid & 63) == 0)
            atomicMax((int*)ws + WS_NM, __float_as_int(nm));
    }

    int gtid = b * 256 + tid;               // 0..32767
    for (int z = gtid; z < P_SL * KH * 2; z += 128 * 256)
        ws[WS_CS + z] = 0.f;
    if (gtid < N_SRC) out[gtid] = 0.f;

    int rr = isx ? r : r - N_SRC;
    float* dst = ws + (isx ? WS_A : WS_B2);
    for (int pi = 0; pi < 32; pi += 4) {    // 4 independent chains for ILP
        int p0 = q * 32 + pi;
        const float4* xi0 = (const float4*)(xis + (p0 + 0) * D_DIM);
        const float4* xi1 = (const float4*)(xis + (p0 + 1) * D_DIM);
        const float4* xi2 = (const float4*)(xis + (p0 + 2) * D_DIM);
        const float4* xi3 = (const float4*)(xis + (p0 + 3) * D_DIM);
        float a0 = 0.f, a1 = 0.f, a2 = 0.f, a3 = 0.f;
#pragma unroll
        for (int j = 0; j < 16; ++j) {
            float4 u0 = xi0[j], u1 = xi1[j], u2 = xi2[j], u3 = xi3[j];
            a0 = fmaf(row[j].x, u0.x, a0); a0 = fmaf(row[j].y, u0.y, a0);
            a0 = fmaf(row[j].z, u0.z, a0); a0 = fmaf(row[j].w, u0.w, a0);
            a1 = fmaf(row[j].x, u1.x, a1); a1 = fmaf(row[j].y, u1.y, a1);
            a1 = fmaf(row[j].z, u1.z, a1); a1 = fmaf(row[j].w, u1.w, a1);
            a2 = fmaf(row[j].x, u2.x, a2); a2 = fmaf(row[j].y, u2.y, a2);
            a2 = fmaf(row[j].z, u2.z, a2); a2 = fmaf(row[j].w, u2.w, a2);
            a3 = fmaf(row[j].x, u3.x, a3); a3 = fmaf(row[j].y, u3.y, a3);
            a3 = fmaf(row[j].z, u3.z, a3); a3 = fmaf(row[j].w, u3.w, a3);
        }
        dst[(size_t)(p0 + 0) * N_SRC + rr] = a0;  // unscaled; sf folded later
        dst[(size_t)(p0 + 1) * N_SRC + rr] = a1;
        dst[(size_t)(p0 + 2) * N_SRC + rr] = a2;
        dst[(size_t)(p0 + 3) * N_SRC + rr] = a3;
    }
}

// kB: adjoint NDFT, lane = POINT, k via per-lane register accumulators
// accC[64]/accS[64] + complex-rotation recurrence (1 sincos per point per 16
// k's). Inner loop: pure full-rate FMA, zero loads. Butterfly reduce-scatter
// (shfl_xor) -> lane l holds wave total for k-index l -> LDS atomic across 4
// waves -> wk-weighted global atomic. grid (8 chunks of 1024 points, 64 p).
__global__ __launch_bounds__(256) void kB(const float* __restrict__ xw,
                                          const float* __restrict__ scale,
                                          float* __restrict__ ws) {
    __shared__ int skmin, skmax;
    __shared__ float sC[64], sS[64];
    int tid = threadIdx.x;
    int chunk = blockIdx.x, p = blockIdx.y;
    if (tid == 0) { skmin = 0x7fffffff; skmax = 0; }
    __syncthreads();
    float nm = __int_as_float(((const int*)ws)[WS_NM]);
    float sf = 0.3f / nm;
    float sr = scale[0] * sf;
    float a = TWO_PI2 * sr * sr;            // 2*pi^2*sigma^2
    float la = logf(a);
    for (int k = tid + 1; k <= KH; k += 256) {
        float logv = 32.f * la + 63.f * logf((float)k)
                   - a * (float)k * (float)k - LGAMMA32;
        if (logv > LOG_THRESH) { atomicMin(&skmin, k); atomicMax(&skmax, k); }
    }
    __syncthreads();
    int kmin = skmin, kmax = skmax;
    if (kmax == 0) return;                  // block-uniform
    int kcnt = kmax - kmin + 1;             // ~58 expected; loop handles any
    int lane = tid & 63;

    // load this thread's 4 points (coalesced), precompute per-point phase step
    int base = chunk * 1024 + tid;
    const float* ap = ws + WS_A + (size_t)p * N_SRC;
    float pa_[4], pw_[4], th_[4], rc_[4], rs_[4];
#pragma unroll
    for (int j = 0; j < 4; ++j) {
        pa_[j] = ap[base + 256 * j];
        pw_[j] = xw[base + 256 * j];
        th_[j] = pa_[j] * sf;               // revolutions per k-step
        sincos2pi(th_[j], rs_[j], rc_[j]);  // rotation ratio e^{2*pi*i*th}
    }

    for (int kbase = 0; kbase < kcnt; kbase += 64) {
        __syncthreads();                    // prev pass tail done
        if (tid < 64) { sC[tid] = 0.f; sS[tid] = 0.f; }
        __syncthreads();

        float accC[64], accS[64];
        float pc_[4], ps_[4];
#pragma unroll
        for (int blk = 0; blk < 4; ++blk) { // re-sync sincos every 16 steps
            float f0 = (float)(kmin + kbase + blk * 16);
#pragma unroll
            for (int j = 0; j < 4; ++j) {
                float t0 = th_[j] * f0;
                float ss0, cc0; sincos2pi(t0, ss0, cc0);
                pc_[j] = cc0 * pw_[j];      // fold w into the rotating phasor
                ps_[j] = ss0 * pw_[j];
            }
#pragma unroll
            for (int u = 0; u < 16; ++u) {
                int i = blk * 16 + u;
                accC[i] = (pc_[0] + pc_[1]) + (pc_[2] + pc_[3]);
                accS[i] = (ps_[0] + ps_[1]) + (ps_[2] + ps_[3]);
#pragma unroll
                for (int j = 0; j < 4; ++j) {
                    float nc = fmaf(pc_[j], rc_[j], -(ps_[j] * rs_[j]));
                    float ns = fmaf(ps_[j], rc_[j],  pc_[j] * rs_[j]);
                    pc_[j] = nc; ps_[j] = ns;
                }
            }
        }

        // butterfly reduce-scatter over 64 lanes: lane l ends with the wave
        // total of original accC[l]/accS[l]. All indices compile-time static.
#pragma unroll
        for (int h = 32; h >= 1; h >>= 1) {
            bool hb = (lane & h) != 0;
#pragma unroll
            for (int i = 0; i < h; ++i) {
                float sc = hb ? accC[i]     : accC[i + h];  // send not-kept half
                float ssv = hb ? accS[i]     : accS[i + h];
                float kc = hb ? accC[i + h] : accC[i];      // keep own half
                float ks = hb ? accS[i + h] : accS[i];
                accC[i] = kc + __shfl_xor(sc, h, 64);
                accS[i] = ks + __shfl_xor(ssv, h, 64);
            }
        }
        atomicAdd(&sC[lane], accC[0]);      // 4 waves x 64 slots: 4-way only
        atomicAdd(&sS[lane], accS[0]);
        __syncthreads();

        int ki = kbase + tid;
        if (tid < 64 && ki < kcnt) {
            int kk = kmin + ki;
            float logv = 32.f * la + 63.f * logf((float)kk)
                       - a * (float)kk * (float)kk - LGAMMA32;
            float wk = ((kk == KH) ? 1.f : 2.f) * expf(logv) * (1.f / (float)P_SL);
            atomicAdd(ws + WS_CS + ((size_t)p * KH + ki) * 2 + 0, wk * sC[tid]);
            atomicAdd(ws + WS_CS + ((size_t)p * KH + ki) * 2 + 1, wk * sS[tid]);
        }
    }
}

// kC: forward NDFT with complex-rotation over k (1 sincos per 8 k's per (m,p)
// instead of per k). CS pairs are block-uniform -> s_load. grid (32, 16).
__global__ __launch_bounds__(256) void kC(const float* __restrict__ scale,
                                          float* __restrict__ ws,
                                          float* __restrict__ out) {
    __shared__ int skmin, skmax;
    int tid = threadIdx.x;
    if (tid == 0) { skmin = 0x7fffffff; skmax = 0; }
    __syncthreads();
    float nm = __int_as_float(((const int*)ws)[WS_NM]);
    float sf = 0.3f / nm;
    float sr = scale[0] * sf;
    float a = TWO_PI2 * sr * sr;
    float la = logf(a);
    for (int k = tid + 1; k <= KH; k += 256) {
        float logv = 32.f * la + 63.f * logf((float)k)
                   - a * (float)k * (float)k - LGAMMA32;
        if (logv > LOG_THRESH) { atomicMin(&skmin, k); atomicMax(&skmax, k); }
    }
    __syncthreads();
    int kmin = skmin, kmax = skmax;
    if (kmax == 0) return;                  // out already zeroed by kA
    int kcnt = kmax - kmin + 1;
    int m = blockIdx.x * 256 + tid;
    int pg = blockIdx.y;
    float sum = 0.f;
    for (int pi = 0; pi < 4; ++pi) {
        int p = pg * 4 + pi;
        float bm = ws[WS_B2 + (size_t)p * N_SRC + m] * sf;
        const float2* cs = (const float2*)(ws + WS_CS) + (size_t)p * KH;
        float cr, crs; sincos2pi(bm, crs, cr);       // rotation ratio e^{2*pi*i*bm}
        for (int ib = 0; ib < kcnt; ib += 8) {       // re-sync sincos every 8 k
            float t0 = bm * (float)(kmin + ib);
            float c, s; sincos2pi(t0, s, c);
#pragma unroll
            for (int u = 0; u < 8; ++u) {
                int i = ib + u;
                if (i < kcnt) {                      // block-uniform branch
                    float2 q = cs[i];                // uniform -> s_load
                    sum = fmaf(q.x, c, sum);
                    sum = fmaf(q.y, s, sum);
                }
                float nc = fmaf(c, cr, -(s * crs));
                s = fmaf(s, cr, c * crs);
                c = nc;
            }
        }
    }
    atomicAdd(out + m, sum);
}

extern "C" void kernel_launch(void* const* d_in, const int* in_sizes, int n_in,
                              void* d_out, int out_size, void* d_ws, size_t ws_size,
                              hipStream_t stream) {
    const float* x     = (const float*)d_in[0];
    const float* y     = (const float*)d_in[1];
    const float* xw    = (const float*)d_in[2];
    const float* scale = (const float*)d_in[3];
    const float* xis   = (const float*)d_in[4];
    float* ws  = (float*)d_ws;
    float* out = (float*)d_out;

    kA<<<dim3(128),      dim3(256), 0, stream>>>(x, y, xis, ws, out);
    kB<<<dim3(8, 64),    dim3(256), 0, stream>>>(xw, scale, ws);
    kC<<<dim3(32, 16),   dim3(256), 0, stream>>>(scale, ws, out);
}

// Round 3
// 101.181 us; speedup vs baseline: 1.1646x; 1.1646x over previous
//
#include <hip/hip_runtime.h>
#include <math.h>

// N=M=8192, d=64, P=64, N_FT=1024 -> folded k = 1..512, active band contiguous
#define N_SRC 8192
#define D_DIM 64
#define P_SL  64
#define KH    512

// ws float offsets. NO host memset: WS_NM uses int atomicMax (0xAAAAAAAA poison
// is negative int -> loses to any positive float bits); CS/out zeroed by kA.
#define WS_NM    0                       // norm_max as float bits, int atomicMax
#define WS_CS    16                      // wk*C, wk*S per (p, k-kmin): P*KH*2
#define WS_A     (WS_CS + P_SL*KH*2)     // UNSCALED projections of x: P*N
#define WS_B2    (WS_A + P_SL*N_SRC)     // UNSCALED projections of y: P*N

#define LOG_THRESH (-23.0259f)           // ln(1e-10): tail adds <1e-6 to out
#define LGAMMA32    78.0922236f
#define TWO_PI2     19.7392088f

__device__ __forceinline__ void sincos2pi(float t, float& s, float& c) {
    // v_sin_f32 / v_cos_f32 take REVOLUTIONS; fract maps into valid range.
    float f = __builtin_amdgcn_fractf(t);
    s = __builtin_amdgcn_sinf(f);
    c = __builtin_amdgcn_cosf(f);
}

// kA: row norms (int atomicMax), unscaled projections (8 slices/thread),
// inline zeroing of CS accumulators and out. grid 512 x 256.
// NOTE (R2 post-mortem): x/y fit in L2, so the 8x re-read is cache-hit, not
// HBM; reducing redundancy by fattening blocks (128 blocks) halves chip
// parallelism and regressed 108->118 us. Keep 512 blocks = 2/CU.
__global__ __launch_bounds__(256) void kA(const float* __restrict__ x,
                                          const float* __restrict__ y,
                                          const float* __restrict__ xis,
                                          float* __restrict__ ws,
                                          float* __restrict__ out) {
    int tid = threadIdx.x, b = blockIdx.x;
    int rblk = b & 63, q = b >> 6;          // q in [0,8): slice eighth, block-uniform
    int r = rblk * 256 + tid;               // 0..16383 over [x; y]
    int isx = (r < N_SRC);
    const float* src = isx ? (x + (size_t)r * D_DIM)
                           : (y + (size_t)(r - N_SRC) * D_DIM);
    float4 row[16];
    const float4* rp = (const float4*)src;
#pragma unroll
    for (int j = 0; j < 16; ++j) row[j] = rp[j];

    if (q == 0) {  // 64 blocks cover all 16384 rows for the norm
        float ss = 0.f;
#pragma unroll
        for (int j = 0; j < 16; ++j) {
            ss = fmaf(row[j].x, row[j].x, ss); ss = fmaf(row[j].y, row[j].y, ss);
            ss = fmaf(row[j].z, row[j].z, ss); ss = fmaf(row[j].w, row[j].w, ss);
        }
        float nm = sqrtf(ss);
        for (int o = 32; o; o >>= 1) nm = fmaxf(nm, __shfl_xor(nm, o, 64));
        if ((tid & 63) == 0)
            atomicMax((int*)ws + WS_NM, __float_as_int(nm));
    }

    int gtid = b * 256 + tid;               // 0..131071
    if (gtid < P_SL * KH * 2) ws[WS_CS + gtid] = 0.f;
    if (gtid < N_SRC)         out[gtid] = 0.f;

    int rr = isx ? r : r - N_SRC;
    float* dst = ws + (isx ? WS_A : WS_B2);
    for (int pi = 0; pi < 8; pi += 4) {     // 2 groups of 4 independent chains
        int p0 = q * 8 + pi;
        const float4* xi0 = (const float4*)(xis + (p0 + 0) * D_DIM);
        const float4* xi1 = (const float4*)(xis + (p0 + 1) * D_DIM);
        const float4* xi2 = (const float4*)(xis + (p0 + 2) * D_DIM);
        const float4* xi3 = (const float4*)(xis + (p0 + 3) * D_DIM);
        float a0 = 0.f, a1 = 0.f, a2 = 0.f, a3 = 0.f;
#pragma unroll
        for (int j = 0; j < 16; ++j) {
            float4 u0 = xi0[j], u1 = xi1[j], u2 = xi2[j], u3 = xi3[j];
            a0 = fmaf(row[j].x, u0.x, a0); a0 = fmaf(row[j].y, u0.y, a0);
            a0 = fmaf(row[j].z, u0.z, a0); a0 = fmaf(row[j].w, u0.w, a0);
            a1 = fmaf(row[j].x, u1.x, a1); a1 = fmaf(row[j].y, u1.y, a1);
            a1 = fmaf(row[j].z, u1.z, a1); a1 = fmaf(row[j].w, u1.w, a1);
            a2 = fmaf(row[j].x, u2.x, a2); a2 = fmaf(row[j].y, u2.y, a2);
            a2 = fmaf(row[j].z, u2.z, a2); a2 = fmaf(row[j].w, u2.w, a2);
            a3 = fmaf(row[j].x, u3.x, a3); a3 = fmaf(row[j].y, u3.y, a3);
            a3 = fmaf(row[j].z, u3.z, a3); a3 = fmaf(row[j].w, u3.w, a3);
        }
        dst[(size_t)(p0 + 0) * N_SRC + rr] = a0;  // unscaled; sf folded later
        dst[(size_t)(p0 + 1) * N_SRC + rr] = a1;
        dst[(size_t)(p0 + 2) * N_SRC + rr] = a2;
        dst[(size_t)(p0 + 3) * N_SRC + rr] = a3;
    }
}

// kB: adjoint NDFT, lane = POINT, k via per-lane register accumulators
// accC[64]/accS[64] + complex-rotation recurrence (1 sincos per point per 16
// k's). Inner loop: pure full-rate FMA, zero loads. Butterfly reduce-scatter
// (shfl_xor) -> lane l holds wave total for k-index l -> LDS atomic across 4
// waves -> wk-weighted global atomic. grid (8 chunks of 1024 points, 64 p).
__global__ __launch_bounds__(256) void kB(const float* __restrict__ xw,
                                          const float* __restrict__ scale,
                                          float* __restrict__ ws) {
    __shared__ int skmin, skmax;
    __shared__ float sC[64], sS[64];
    int tid = threadIdx.x;
    int chunk = blockIdx.x, p = blockIdx.y;
    if (tid == 0) { skmin = 0x7fffffff; skmax = 0; }
    __syncthreads();
    float nm = __int_as_float(((const int*)ws)[WS_NM]);
    float sf = 0.3f / nm;
    float sr = scale[0] * sf;
    float a = TWO_PI2 * sr * sr;            // 2*pi^2*sigma^2
    float la = logf(a);
    for (int k = tid + 1; k <= KH; k += 256) {
        float logv = 32.f * la + 63.f * logf((float)k)
                   - a * (float)k * (float)k - LGAMMA32;
        if (logv > LOG_THRESH) { atomicMin(&skmin, k); atomicMax(&skmax, k); }
    }
    __syncthreads();
    int kmin = skmin, kmax = skmax;
    if (kmax == 0) return;                  // block-uniform
    int kcnt = kmax - kmin + 1;             // ~58 expected; loop handles any
    int lane = tid & 63;

    // load this thread's 4 points (coalesced), precompute per-point phase step
    int base = chunk * 1024 + tid;
    const float* ap = ws + WS_A + (size_t)p * N_SRC;
    float pa_[4], pw_[4], th_[4], rc_[4], rs_[4];
#pragma unroll
    for (int j = 0; j < 4; ++j) {
        pa_[j] = ap[base + 256 * j];
        pw_[j] = xw[base + 256 * j];
        th_[j] = pa_[j] * sf;               // revolutions per k-step
        sincos2pi(th_[j], rs_[j], rc_[j]);  // rotation ratio e^{2*pi*i*th}
    }

    for (int kbase = 0; kbase < kcnt; kbase += 64) {
        __syncthreads();                    // prev pass tail done
        if (tid < 64) { sC[tid] = 0.f; sS[tid] = 0.f; }
        __syncthreads();

        float accC[64], accS[64];
        float pc_[4], ps_[4];
#pragma unroll
        for (int blk = 0; blk < 4; ++blk) { // re-sync sincos every 16 steps
            float f0 = (float)(kmin + kbase + blk * 16);
#pragma unroll
            for (int j = 0; j < 4; ++j) {
                float t0 = th_[j] * f0;
                float ss0, cc0; sincos2pi(t0, ss0, cc0);
                pc_[j] = cc0 * pw_[j];      // fold w into the rotating phasor
                ps_[j] = ss0 * pw_[j];
            }
#pragma unroll
            for (int u = 0; u < 16; ++u) {
                int i = blk * 16 + u;
                accC[i] = (pc_[0] + pc_[1]) + (pc_[2] + pc_[3]);
                accS[i] = (ps_[0] + ps_[1]) + (ps_[2] + ps_[3]);
#pragma unroll
                for (int j = 0; j < 4; ++j) {
                    float nc = fmaf(pc_[j], rc_[j], -(ps_[j] * rs_[j]));
                    float ns = fmaf(ps_[j], rc_[j],  pc_[j] * rs_[j]);
                    pc_[j] = nc; ps_[j] = ns;
                }
            }
        }

        // butterfly reduce-scatter over 64 lanes: lane l ends with the wave
        // total of original accC[l]/accS[l]. All indices compile-time static.
#pragma unroll
        for (int h = 32; h >= 1; h >>= 1) {
            bool hb = (lane & h) != 0;
#pragma unroll
            for (int i = 0; i < h; ++i) {
                float sc = hb ? accC[i]     : accC[i + h];  // send not-kept half
                float ssv = hb ? accS[i]     : accS[i + h];
                float kc = hb ? accC[i + h] : accC[i];      // keep own half
                float ks = hb ? accS[i + h] : accS[i];
                accC[i] = kc + __shfl_xor(sc, h, 64);
                accS[i] = ks + __shfl_xor(ssv, h, 64);
            }
        }
        atomicAdd(&sC[lane], accC[0]);      // 4 waves x 64 slots: 4-way only
        atomicAdd(&sS[lane], accS[0]);
        __syncthreads();

        int ki = kbase + tid;
        if (tid < 64 && ki < kcnt) {
            int kk = kmin + ki;
            float logv = 32.f * la + 63.f * logf((float)kk)
                       - a * (float)kk * (float)kk - LGAMMA32;
            float wk = ((kk == KH) ? 1.f : 2.f) * expf(logv) * (1.f / (float)P_SL);
            atomicAdd(ws + WS_CS + ((size_t)p * KH + ki) * 2 + 0, wk * sC[tid]);
            atomicAdd(ws + WS_CS + ((size_t)p * KH + ki) * 2 + 1, wk * sS[tid]);
        }
    }
}

// kC: forward NDFT with complex-rotation over k (1 sincos per 8 k's per (m,p)
// instead of per k). CS pairs are block-uniform -> s_load. grid (32, 16).
__global__ __launch_bounds__(256) void kC(const float* __restrict__ scale,
                                          float* __restrict__ ws,
                                          float* __restrict__ out) {
    __shared__ int skmin, skmax;
    int tid = threadIdx.x;
    if (tid == 0) { skmin = 0x7fffffff; skmax = 0; }
    __syncthreads();
    float nm = __int_as_float(((const int*)ws)[WS_NM]);
    float sf = 0.3f / nm;
    float sr = scale[0] * sf;
    float a = TWO_PI2 * sr * sr;
    float la = logf(a);
    for (int k = tid + 1; k <= KH; k += 256) {
        float logv = 32.f * la + 63.f * logf((float)k)
                   - a * (float)k * (float)k - LGAMMA32;
        if (logv > LOG_THRESH) { atomicMin(&skmin, k); atomicMax(&skmax, k); }
    }
    __syncthreads();
    int kmin = skmin, kmax = skmax;
    if (kmax == 0) return;                  // out already zeroed by kA
    int kcnt = kmax - kmin + 1;
    int m = blockIdx.x * 256 + tid;
    int pg = blockIdx.y;
    float sum = 0.f;
    for (int pi = 0; pi < 4; ++pi) {
        int p = pg * 4 + pi;
        float bm = ws[WS_B2 + (size_t)p * N_SRC + m] * sf;
        const float2* cs = (const float2*)(ws + WS_CS) + (size_t)p * KH;
        float cr, crs; sincos2pi(bm, crs, cr);       // rotation ratio e^{2*pi*i*bm}
        for (int ib = 0; ib < kcnt; ib += 8) {       // re-sync sincos every 8 k
            float t0 = bm * (float)(kmin + ib);
            float c, s; sincos2pi(t0, s, c);
#pragma unroll
            for (int u = 0; u < 8; ++u) {
                int i = ib + u;
                if (i < kcnt) {                      // block-uniform branch
                    float2 q = cs[i];                // uniform -> s_load
                    sum = fmaf(q.x, c, sum);
                    sum = fmaf(q.y, s, sum);
                }
                float nc = fmaf(c, cr, -(s * crs));
                s = fmaf(s, cr, c * crs);
                c = nc;
            }
        }
    }
    atomicAdd(out + m, sum);
}

extern "C" void kernel_launch(void* const* d_in, const int* in_sizes, int n_in,
                              void* d_out, int out_size, void* d_ws, size_t ws_size,
                              hipStream_t stream) {
    const float* x     = (const float*)d_in[0];
    const float* y     = (const float*)d_in[1];
    const float* xw    = (const float*)d_in[2];
    const float* scale = (const float*)d_in[3];
    const float* xis   = (const float*)d_in[4];
    float* ws  = (float*)d_ws;
    float* out = (float*)d_out;

    kA<<<dim3(512),      dim3(256), 0, stream>>>(x, y, xis, ws, out);
    kB<<<dim3(8, 64),    dim3(256), 0, stream>>>(xw, scale, ws);
    kC<<<dim3(32, 16),   dim3(256), 0, stream>>>(scale, ws, out);
}